// Round 6
// baseline (217.114 us; speedup 1.0000x reference)
//
#include <hip/hip_runtime.h>

typedef __bf16 bf16;
typedef __bf16 bf16x8 __attribute__((ext_vector_type(8), aligned(16)));
typedef float  f32x4  __attribute__((ext_vector_type(4)));

#define B_ 8
#define T_ 16
#define N_ 2048
#define C_ 512

// ---- helpers ----
__device__ inline bf16x8 load8_f32(const float* p) {
    float4 a = *(const float4*)p;
    float4 b = *(const float4*)(p + 4);
    bf16x8 r;
    r[0] = (bf16)a.x; r[1] = (bf16)a.y; r[2] = (bf16)a.z; r[3] = (bf16)a.w;
    r[4] = (bf16)b.x; r[5] = (bf16)b.y; r[6] = (bf16)b.z; r[7] = (bf16)b.w;
    return r;
}

__device__ inline void gload_lds16(const bf16* g, bf16* l) {
    __builtin_amdgcn_global_load_lds(
        (const __attribute__((address_space(1))) void*)g,
        (__attribute__((address_space(3))) void*)l, 16, 0, 0);
}

#define MEMFENCE asm volatile("" ::: "memory")

// One merged prep kernel (unchanged from round 4/5).
__global__ __launch_bounds__(256) void k_prep(
    const float* __restrict__ vd_s, const float* __restrict__ nodes,
    const float* __restrict__ W1, const float* __restrict__ W2,
    const float* __restrict__ b1,
    float* __restrict__ out, bf16* __restrict__ nodes_bf,
    bf16* __restrict__ W1t, bf16* __restrict__ W2t, float* __restrict__ q) {
    __shared__ float sh[32 * 33];
    const int bx = blockIdx.x, tid = threadIdx.x;
    if (bx < 2048) {
        size_t i = ((size_t)bx * 256 + tid) * 16;
        *(bf16x8*)(nodes_bf + i)     = load8_f32(nodes + i);
        *(bf16x8*)(nodes_bf + i + 8) = load8_f32(nodes + i + 8);
    } else if (bx < 2064) {
        int gt = (bx - 2048) * 256 + tid;
        int b = gt >> 9, c = gt & 511;
        float s = 0.f;
#pragma unroll
        for (int t = 0; t < T_; ++t) s += vd_s[(size_t)b * T_ * C_ + t * C_ + c];
        out[b * 2 * C_ + c] = s * (1.0f / T_);
    } else if (bx < 2576) {
        const float* W = (bx < 2320) ? W1 : W2;
        bf16* Wt = (bx < 2320) ? W1t : W2t;
        int idx = (bx < 2320) ? bx - 2064 : bx - 2320;
        int bxx = (idx & 15) * 32, byy = (idx >> 4) * 32;
        int tx = tid & 31, ty = tid >> 5;
#pragma unroll
        for (int r = 0; r < 32; r += 8)
            sh[(ty + r) * 33 + tx] = W[(size_t)(byy + ty + r) * C_ + bxx + tx];
        __syncthreads();
#pragma unroll
        for (int r = 0; r < 32; r += 8)
            Wt[(size_t)(bxx + ty + r) * C_ + byy + tx] = (bf16)sh[tx * 33 + ty + r];
    } else {
        int j = bx - 2576;
#pragma unroll
        for (int h = 0; h < 2; ++h) {
            int c = h * 256 + tid;
            float s = 0.f;
#pragma unroll
            for (int kk = 0; kk < 32; ++kk) {
                int k = j * 32 + kk;
                s += b1[k] * W2[(size_t)k * C_ + c];
            }
            atomicAdd(&q[c], s);
        }
    }
}

// 128x128-tile NT GEMM (round-3 structure): C = A*B^T + bias.  Used for Gt, H2.
__global__ __launch_bounds__(256) void gemm_nt(
    const bf16* __restrict__ A, size_t strideA,
    const bf16* __restrict__ Bm, size_t strideB,
    const float* __restrict__ bias,
    bf16* __restrict__ C, size_t strideC,
    int N, int K) {
    __shared__ __attribute__((aligned(16))) bf16 lA[128 * 64];
    __shared__ __attribute__((aligned(16))) bf16 lB[128 * 64];
    const int tid = threadIdx.x;
    const int lane = tid & 63, w = tid >> 6;
    const int wm = w >> 1, wn = w & 1;
    const int z = blockIdx.z;
    const int bm = blockIdx.x * 128, bn = blockIdx.y * 128;
    const bf16* Ab = A + (size_t)z * strideA;
    const bf16* Bb = Bm + (size_t)z * strideB;

    f32x4 acc[4][4];
#pragma unroll
    for (int i = 0; i < 4; ++i)
#pragma unroll
        for (int j = 0; j < 4; ++j) acc[i][j] = f32x4{0.f, 0.f, 0.f, 0.f};

    const int nkt = K >> 6;
    for (int kt = 0; kt < nkt; ++kt) {
#pragma unroll
        for (int c = 0; c < 4; ++c) {
            int ca = c * 256 + tid;
            int row = ca >> 3;
            int qd = (ca & 7) ^ (row & 7);
            gload_lds16(Ab + (size_t)(bm + row) * K + kt * 64 + qd * 8,
                        lA + c * 2048 + w * 512);
            gload_lds16(Bb + (size_t)(bn + row) * K + kt * 64 + qd * 8,
                        lB + c * 2048 + w * 512);
        }
        __syncthreads();

        bf16x8 af[2][4], bfr[2][4];
#pragma unroll
        for (int ks = 0; ks < 2; ++ks) {
            int y = ks * 4 + (lane >> 4);
#pragma unroll
            for (int i = 0; i < 4; ++i) {
                int ra = wm * 64 + i * 16 + (lane & 15);
                int rb = wn * 64 + i * 16 + (lane & 15);
                af[ks][i]  = *(const bf16x8*)&lA[ra * 64 + ((y ^ (ra & 7)) * 8)];
                bfr[ks][i] = *(const bf16x8*)&lB[rb * 64 + ((y ^ (rb & 7)) * 8)];
            }
        }
#pragma unroll
        for (int ks = 0; ks < 2; ++ks)
#pragma unroll
            for (int i = 0; i < 4; ++i)
#pragma unroll
                for (int j = 0; j < 4; ++j)
                    acc[i][j] = __builtin_amdgcn_mfma_f32_16x16x32_bf16(
                        af[ks][i], bfr[ks][j], acc[i][j], 0, 0, 0);
        __syncthreads();
    }

    bf16* Cb = C + (size_t)z * strideC;
#pragma unroll
    for (int i = 0; i < 4; ++i) {
#pragma unroll
        for (int j = 0; j < 4; ++j) {
            int col = bn + wn * 64 + j * 16 + (lane & 15);
            float bv = bias ? bias[col] : 0.f;
#pragma unroll
            for (int r = 0; r < 4; ++r) {
                int row = bm + wm * 64 + i * 16 + (lane >> 4) * 4 + r;
                Cb[(size_t)row * N + col] = (bf16)(acc[i][j][r] + bv);
            }
        }
    }
}

// 256x256-tile derived-waits NT GEMM for P = exp(H2 @ nodes^T), fused row-sums l.
// Fixed geometry: M=N=2048, K=512 (nkt=8), 8 batches, grid 512 x 512 threads.
// Per K-tile: 2 phases. ph0: read A(16 b128, cached) + B-even(4), MFMA j01.
//             ph1: read B-odd(4), MFMA j23. Stage: ph0 issues B-odd(t+1) [2 loads],
// ph1 issues A+B-even(t+2) [6 loads]. Steady-state wait: vmcnt(8).
__global__ __launch_bounds__(512, 2) void gemm256(
    const bf16* __restrict__ A, const bf16* __restrict__ Bm,
    bf16* __restrict__ P, float* __restrict__ l) {
    __shared__ __attribute__((aligned(16))) bf16 ls[2][2][16384];   // 128 KiB
    const int tid = threadIdx.x;
    const int lane = tid & 63, w = tid >> 6;
    const int wm = w >> 2, wn = w & 3;            // 2 x 4 wave grid
    const int id = blockIdx.x;
    const int sw = (id & 7) * 64 + (id >> 3);     // XCD x <- batch x
    const int z = sw >> 6, t = sw & 63;
    const int bm = (t >> 3) * 256, bn = (t & 7) * 256;
    const bf16* Ab = A + (size_t)z * N_ * C_;
    const bf16* Bb = Bm + (size_t)z * N_ * C_;
    const int K = C_;

    f32x4 acc[8][4];
#pragma unroll
    for (int i = 0; i < 8; ++i)
#pragma unroll
        for (int j = 0; j < 4; ++j) acc[i][j] = f32x4{0.f, 0.f, 0.f, 0.f};

    // A tile rows [0,256) all 8 chunks: 4 wave-groups. B split even/odd 32-row
    // halves of each 64-row block: 2 wave-groups each.
#define STAGE_A_BE(kt_, buf_)                                                     \
    {                                                                             \
        _Pragma("unroll")                                                         \
        for (int g = 0; g < 4; ++g) {                                             \
            int p = g * 512 + tid;                                                \
            int row = p >> 3;                                                     \
            int yl = (p & 7) ^ (row & 7);                                         \
            gload_lds16(Ab + (size_t)(bm + row) * K + (kt_) * 64 + yl * 8,        \
                        &ls[buf_][0][(g * 512 + w * 64) * 8]);                    \
        }                                                                         \
        _Pragma("unroll")                                                         \
        for (int g = 0; g < 2; ++g) {                                             \
            int p = g * 512 + tid;                                                \
            int row = (p >> 8) * 64 + ((p >> 3) & 31);                            \
            int yl = (p & 7) ^ (row & 7);                                         \
            gload_lds16(Bb + (size_t)(bn + row) * K + (kt_) * 64 + yl * 8,        \
                        &ls[buf_][1][(g * 2 + (w >> 2)) * 4096 + (w & 3) * 512]); \
        }                                                                         \
    }
#define STAGE_BO(kt_, buf_)                                                       \
    {                                                                             \
        _Pragma("unroll")                                                         \
        for (int g = 0; g < 2; ++g) {                                             \
            int p = g * 512 + tid;                                                \
            int row = (p >> 8) * 64 + 32 + ((p >> 3) & 31);                       \
            int yl = (p & 7) ^ (row & 7);                                         \
            gload_lds16(Bb + (size_t)(bn + row) * K + (kt_) * 64 + yl * 8,        \
                        &ls[buf_][1][(g * 2 + (w >> 2)) * 4096 + 2048 +           \
                                     (w & 3) * 512]);                             \
        }                                                                         \
    }

    // prologue: A+Be(0) [6], Bo(0) [2], A+Be(1) [6]
    STAGE_A_BE(0, 0);
    STAGE_BO(0, 0);
    STAGE_A_BE(1, 1);
    asm volatile("s_waitcnt vmcnt(8)" ::: "memory");   // A+Be(0) landed
    __builtin_amdgcn_s_barrier();
    MEMFENCE;

#pragma unroll
    for (int t = 0; t < 8; ++t) {
        const int cur = t & 1;
        const bf16* lA = &ls[cur][0][0];
        const bf16* lB = &ls[cur][1][0];

        // ---------- ph0: A(all, cached) + B-even; MFMA j = 0,1 ----------
        bf16x8 af[8][2], bfv[2][2];
#pragma unroll
        for (int i = 0; i < 8; ++i) {
            int ra = wm * 128 + i * 16 + (lane & 15);
#pragma unroll
            for (int ks = 0; ks < 2; ++ks) {
                int yl = ks * 4 + (lane >> 4);
                af[i][ks] = *(const bf16x8*)&lA[ra * 64 + ((yl ^ (ra & 7)) * 8)];
            }
        }
#pragma unroll
        for (int j = 0; j < 2; ++j) {
            int rb = wn * 64 + j * 16 + (lane & 15);
#pragma unroll
            for (int ks = 0; ks < 2; ++ks) {
                int yl = ks * 4 + (lane >> 4);
                bfv[j][ks] = *(const bf16x8*)&lB[rb * 64 + ((yl ^ (rb & 7)) * 8)];
            }
        }
        if (t < 7) STAGE_BO(t + 1, (t + 1) & 1);       // region freed at ph1(t-1)
        if (t < 7) asm volatile("s_waitcnt vmcnt(8)" ::: "memory");  // Bo(t) landed
        else       asm volatile("s_waitcnt vmcnt(0)" ::: "memory");
        MEMFENCE;
        __builtin_amdgcn_s_barrier();
        asm volatile("s_waitcnt lgkmcnt(0)" ::: "memory");
        __builtin_amdgcn_sched_barrier(0);
        __builtin_amdgcn_s_setprio(1);
#pragma unroll
        for (int ks = 0; ks < 2; ++ks)
#pragma unroll
            for (int i = 0; i < 8; ++i)
#pragma unroll
                for (int j = 0; j < 2; ++j)
                    acc[i][j] = __builtin_amdgcn_mfma_f32_16x16x32_bf16(
                        af[i][ks], bfv[j][ks], acc[i][j], 0, 0, 0);
        __builtin_amdgcn_s_setprio(0);
        MEMFENCE;
        __builtin_amdgcn_s_barrier();
        MEMFENCE;

        // ---------- ph1: B-odd (A reused); MFMA j = 2,3 ----------
#pragma unroll
        for (int j = 0; j < 2; ++j) {
            int rb = wn * 64 + 32 + j * 16 + (lane & 15);
#pragma unroll
            for (int ks = 0; ks < 2; ++ks) {
                int yl = ks * 4 + (lane >> 4);
                bfv[j][ks] = *(const bf16x8*)&lB[rb * 64 + ((yl ^ (rb & 7)) * 8)];
            }
        }
        if (t < 6) STAGE_A_BE(t + 2, cur);             // regions freed at ph0(t)
        if (t < 6)      asm volatile("s_waitcnt vmcnt(8)" ::: "memory");
        else if (t == 6) asm volatile("s_waitcnt vmcnt(2)" ::: "memory");
        MEMFENCE;
        __builtin_amdgcn_s_barrier();
        asm volatile("s_waitcnt lgkmcnt(0)" ::: "memory");
        __builtin_amdgcn_sched_barrier(0);
        __builtin_amdgcn_s_setprio(1);
#pragma unroll
        for (int ks = 0; ks < 2; ++ks)
#pragma unroll
            for (int i = 0; i < 8; ++i)
#pragma unroll
                for (int j = 0; j < 2; ++j)
                    acc[i][2 + j] = __builtin_amdgcn_mfma_f32_16x16x32_bf16(
                        af[i][ks], bfv[j][ks], acc[i][2 + j], 0, 0, 0);
        __builtin_amdgcn_s_setprio(0);
        MEMFENCE;
        __builtin_amdgcn_s_barrier();
        MEMFENCE;
    }

    // ---- epilogue: P = exp(acc), fused row sums l (shfl-reduce + atomics) ----
    bf16* Pb = P + (size_t)z * N_ * N_;
    float* lb = l + z * N_;
#pragma unroll
    for (int fi = 0; fi < 8; ++fi) {
#pragma unroll
        for (int r = 0; r < 4; ++r) {
            int row = bm + wm * 128 + fi * 16 + (lane >> 4) * 4 + r;
            float rp = 0.f;
#pragma unroll
            for (int fj = 0; fj < 4; ++fj) {
                float v = __expf(fminf(acc[fi][fj][r], 30.f));
                int col = bn + wn * 64 + fj * 16 + (lane & 15);
                Pb[(size_t)row * N_ + col] = (bf16)v;
                rp += v;
            }
            rp += __shfl_xor(rp, 1);
            rp += __shfl_xor(rp, 2);
            rp += __shfl_xor(rp, 4);
            rp += __shfl_xor(rp, 8);
            if ((lane & 15) == 0) atomicAdd(&lb[row], rp);
        }
    }
#undef STAGE_A_BE
#undef STAGE_BO
}

// Single pass over P: w[j] += sum_i P[i][j] / l[i]   (16-row strips)
__global__ __launch_bounds__(256) void k_w(const bf16* __restrict__ P,
                                           const float* __restrict__ l,
                                           float* __restrict__ w) {
    __shared__ float ri[16];
    const int tid = threadIdx.x, b = blockIdx.y, rb = blockIdx.x;
    if (tid < 16) ri[tid] = 1.0f / l[b * N_ + rb * 16 + tid];
    __syncthreads();
    const bf16* src = P + (size_t)b * N_ * N_ + (size_t)rb * 16 * N_;
    const int j0 = tid * 8;
    float acc8[8] = {0.f, 0.f, 0.f, 0.f, 0.f, 0.f, 0.f, 0.f};
#pragma unroll
    for (int r = 0; r < 16; ++r) {
        bf16x8 v = *(const bf16x8*)&src[(size_t)r * N_ + j0];
        float rr = ri[r];
#pragma unroll
        for (int e = 0; e < 8; ++e) acc8[e] += rr * (float)v[e];
    }
    float* wb = w + b * N_;
#pragma unroll
    for (int e = 0; e < 8; ++e) atomicAdd(&wb[j0 + e], acc8[e]);
}

// gpacc[b][c] += sum_{j in 64-row slab} (w[b][j]+1) * nodes_bf[b][j][c]
__global__ void k_gp(const bf16* __restrict__ nodes_bf, const float* __restrict__ w,
                     float* __restrict__ gpacc) {
    const int tid = threadIdx.x;
    const int b = blockIdx.y;
    const int j0 = blockIdx.x * 64;
    const int cc = (tid & 63) * 8, jr = tid >> 6;
    const bf16* nb = nodes_bf + (size_t)b * N_ * C_;
    const float* wb = w + b * N_;
    float acc8[8] = {0.f, 0.f, 0.f, 0.f, 0.f, 0.f, 0.f, 0.f};
    for (int j = jr; j < 64; j += 4) {
        float wj = wb[j0 + j] + 1.0f;
        bf16x8 nv = *(const bf16x8*)&nb[(size_t)(j0 + j) * C_ + cc];
#pragma unroll
        for (int e = 0; e < 8; ++e) acc8[e] += wj * (float)nv[e];
    }
#pragma unroll
    for (int e = 0; e < 8; ++e) atomicAdd(&gpacc[b * C_ + cc + e], acc8[e]);
}

__global__ void k_fin(const float* __restrict__ gpacc, float* __restrict__ out) {
    int gt = blockIdx.x * 256 + threadIdx.x;
    int b = gt >> 9, c = gt & 511;
    out[b * 2 * C_ + C_ + c] = gpacc[b * C_ + c] * (1.0f / N_);
}

extern "C" void kernel_launch(void* const* d_in, const int* in_sizes, int n_in,
                              void* d_out, int out_size, void* d_ws, size_t ws_size,
                              hipStream_t stream) {
    const float* vd_s  = (const float*)d_in[0];
    const float* nodes = (const float*)d_in[1];
    const float* W1    = (const float*)d_in[2];
    const float* b1    = (const float*)d_in[3];
    const float* W2    = (const float*)d_in[4];
    // d_in[5] (b2) adds a row-constant to adj -> cancels in row-softmax -> unused
    float* out = (float*)d_out;

    char* ws = (char*)d_ws;
    bf16*  nodes_bf = (bf16*)(ws);                                   // 16 MB
    bf16*  H2       = (bf16*)(ws + ((size_t)16 << 20));              // 16 MB
    bf16*  P        = (bf16*)(ws + ((size_t)32 << 20));              // 64 MB
    bf16*  W1t      = (bf16*)(ws + ((size_t)96 << 20));              // 512 KB
    bf16*  W2t      = (bf16*)(ws + ((size_t)96 << 20) + (512u << 10));
    bf16*  Gt       = (bf16*)(ws + ((size_t)96 << 20) + (1024u << 10));
    char*  fbase    = ws + ((size_t)96 << 20) + (1536u << 10);
    float* q        = (float*)(fbase);                     // 4 KB
    float* w        = (float*)(fbase + 4096);              // 64 KB
    float* gpacc    = (float*)(fbase + 4096 + 65536);      // 16 KB
    float* l        = (float*)(fbase + 4096 + 65536 + 16384);  // 64 KB

    // zero q + w + gpacc + l (contiguous 148 KB)
    (void)hipMemsetAsync(q, 0, 4096 + 65536 + 16384 + 65536, stream);

    k_prep<<<2592, 256, 0, stream>>>(vd_s, nodes, W1, W2, b1,
                                     out, nodes_bf, W1t, W2t, q);

    // Gt[c][k] = sum_m W2t[c][m]*W1t[k][m]   (M=N=K=512)
    gemm_nt<<<dim3(4, 4, 1), 256, 0, stream>>>(
        W2t, 0, W1t, 0, nullptr, Gt, 0, C_, C_);
    // H2[b] = nodes_bf[b] @ Gt^T + q[col]   (M=2048, N=512, K=512)
    gemm_nt<<<dim3(16, 4, 8), 256, 0, stream>>>(
        nodes_bf, (size_t)N_ * C_, Gt, 0, q,
        H2, (size_t)N_ * C_, C_, C_);
    // P[b] = exp(H2[b] @ nodes_bf[b]^T), l[b][i] = row sums
    gemm256<<<512, 512, 0, stream>>>(H2, nodes_bf, P, l);

    k_w<<<dim3(128, 8), 256, 0, stream>>>(P, l, w);
    k_gp<<<dim3(32, 8), 256, 0, stream>>>(nodes_bf, w, gpacc);
    k_fin<<<16, 256, 0, stream>>>(gpacc, out);
}

// Round 7
// 168.494 us; speedup vs baseline: 1.2886x; 1.2886x over previous
//
#include <hip/hip_runtime.h>

typedef __bf16 bf16;
typedef __bf16 bf16x8 __attribute__((ext_vector_type(8), aligned(16)));
typedef float  f32x4  __attribute__((ext_vector_type(4)));

#define B_ 8
#define T_ 16
#define N_ 2048
#define C_ 512

// ---- helpers ----
__device__ inline bf16x8 load8_f32(const float* p) {
    float4 a = *(const float4*)p;
    float4 b = *(const float4*)(p + 4);
    bf16x8 r;
    r[0] = (bf16)a.x; r[1] = (bf16)a.y; r[2] = (bf16)a.z; r[3] = (bf16)a.w;
    r[4] = (bf16)b.x; r[5] = (bf16)b.y; r[6] = (bf16)b.z; r[7] = (bf16)b.w;
    return r;
}

__device__ inline void gload_lds16(const bf16* g, bf16* l) {
    __builtin_amdgcn_global_load_lds(
        (const __attribute__((address_space(1))) void*)g,
        (__attribute__((address_space(3))) void*)l, 16, 0, 0);
}

// One merged prep kernel (unchanged).
__global__ __launch_bounds__(256) void k_prep(
    const float* __restrict__ vd_s, const float* __restrict__ nodes,
    const float* __restrict__ W1, const float* __restrict__ W2,
    const float* __restrict__ b1,
    float* __restrict__ out, bf16* __restrict__ nodes_bf,
    bf16* __restrict__ W1t, bf16* __restrict__ W2t, float* __restrict__ q) {
    __shared__ float sh[32 * 33];
    const int bx = blockIdx.x, tid = threadIdx.x;
    if (bx < 2048) {
        size_t i = ((size_t)bx * 256 + tid) * 16;
        *(bf16x8*)(nodes_bf + i)     = load8_f32(nodes + i);
        *(bf16x8*)(nodes_bf + i + 8) = load8_f32(nodes + i + 8);
    } else if (bx < 2064) {
        int gt = (bx - 2048) * 256 + tid;
        int b = gt >> 9, c = gt & 511;
        float s = 0.f;
#pragma unroll
        for (int t = 0; t < T_; ++t) s += vd_s[(size_t)b * T_ * C_ + t * C_ + c];
        out[b * 2 * C_ + c] = s * (1.0f / T_);
    } else if (bx < 2576) {
        const float* W = (bx < 2320) ? W1 : W2;
        bf16* Wt = (bx < 2320) ? W1t : W2t;
        int idx = (bx < 2320) ? bx - 2064 : bx - 2320;
        int bxx = (idx & 15) * 32, byy = (idx >> 4) * 32;
        int tx = tid & 31, ty = tid >> 5;
#pragma unroll
        for (int r = 0; r < 32; r += 8)
            sh[(ty + r) * 33 + tx] = W[(size_t)(byy + ty + r) * C_ + bxx + tx];
        __syncthreads();
#pragma unroll
        for (int r = 0; r < 32; r += 8)
            Wt[(size_t)(bxx + ty + r) * C_ + byy + tx] = (bf16)sh[tx * 33 + ty + r];
    } else {
        int j = bx - 2576;
#pragma unroll
        for (int h = 0; h < 2; ++h) {
            int c = h * 256 + tid;
            float s = 0.f;
#pragma unroll
            for (int kk = 0; kk < 32; ++kk) {
                int k = j * 32 + kk;
                s += b1[k] * W2[(size_t)k * C_ + c];
            }
            atomicAdd(&q[c], s);
        }
    }
}

// 128x128-tile NT GEMM (round-3 measured structure).
// EXPOUT: C = exp(min(acc,30)), and row-sums accumulated into lout (atomics).
// else:   C = acc + bias[n].
template <bool EXPOUT>
__global__ __launch_bounds__(256) void gemm_nt(
    const bf16* __restrict__ A, size_t strideA,
    const bf16* __restrict__ Bm, size_t strideB,
    const float* __restrict__ bias, float* __restrict__ lout,
    bf16* __restrict__ C, size_t strideC,
    int N, int K) {
    __shared__ __attribute__((aligned(16))) bf16 lA[128 * 64];
    __shared__ __attribute__((aligned(16))) bf16 lB[128 * 64];
    const int tid = threadIdx.x;
    const int lane = tid & 63, w = tid >> 6;
    const int wm = w >> 1, wn = w & 1;
    const int z = blockIdx.z;
    const int bm = blockIdx.x * 128, bn = blockIdx.y * 128;
    const bf16* Ab = A + (size_t)z * strideA;
    const bf16* Bb = Bm + (size_t)z * strideB;

    f32x4 acc[4][4];
#pragma unroll
    for (int i = 0; i < 4; ++i)
#pragma unroll
        for (int j = 0; j < 4; ++j) acc[i][j] = f32x4{0.f, 0.f, 0.f, 0.f};

    const int nkt = K >> 6;
    for (int kt = 0; kt < nkt; ++kt) {
#pragma unroll
        for (int c = 0; c < 4; ++c) {
            int ca = c * 256 + tid;
            int row = ca >> 3;
            int qd = (ca & 7) ^ (row & 7);
            gload_lds16(Ab + (size_t)(bm + row) * K + kt * 64 + qd * 8,
                        lA + c * 2048 + w * 512);
            gload_lds16(Bb + (size_t)(bn + row) * K + kt * 64 + qd * 8,
                        lB + c * 2048 + w * 512);
        }
        __syncthreads();

        bf16x8 af[2][4], bfr[2][4];
#pragma unroll
        for (int ks = 0; ks < 2; ++ks) {
            int y = ks * 4 + (lane >> 4);
#pragma unroll
            for (int i = 0; i < 4; ++i) {
                int ra = wm * 64 + i * 16 + (lane & 15);
                int rb = wn * 64 + i * 16 + (lane & 15);
                af[ks][i]  = *(const bf16x8*)&lA[ra * 64 + ((y ^ (ra & 7)) * 8)];
                bfr[ks][i] = *(const bf16x8*)&lB[rb * 64 + ((y ^ (rb & 7)) * 8)];
            }
        }
#pragma unroll
        for (int ks = 0; ks < 2; ++ks)
#pragma unroll
            for (int i = 0; i < 4; ++i)
#pragma unroll
                for (int j = 0; j < 4; ++j)
                    acc[i][j] = __builtin_amdgcn_mfma_f32_16x16x32_bf16(
                        af[ks][i], bfr[ks][j], acc[i][j], 0, 0, 0);
        __syncthreads();
    }

    bf16* Cb = C + (size_t)z * strideC;
    if constexpr (!EXPOUT) {
#pragma unroll
        for (int i = 0; i < 4; ++i) {
#pragma unroll
            for (int j = 0; j < 4; ++j) {
                int col = bn + wn * 64 + j * 16 + (lane & 15);
                float bv = bias ? bias[col] : 0.f;
#pragma unroll
                for (int r = 0; r < 4; ++r) {
                    int row = bm + wm * 64 + i * 16 + (lane >> 4) * 4 + r;
                    Cb[(size_t)row * N + col] = (bf16)(acc[i][j][r] + bv);
                }
            }
        }
    } else {
        float* lb = lout + z * N_;
        float rp[4][4];   // [i][r] partial row sums (this wave's 64 cols)
#pragma unroll
        for (int i = 0; i < 4; ++i)
#pragma unroll
            for (int r = 0; r < 4; ++r) rp[i][r] = 0.f;
#pragma unroll
        for (int i = 0; i < 4; ++i) {
#pragma unroll
            for (int j = 0; j < 4; ++j) {
                int col = bn + wn * 64 + j * 16 + (lane & 15);
#pragma unroll
                for (int r = 0; r < 4; ++r) {
                    int row = bm + wm * 64 + i * 16 + (lane >> 4) * 4 + r;
                    float v = __expf(fminf(acc[i][j][r], 30.f));
                    Cb[(size_t)row * N + col] = (bf16)v;
                    rp[i][r] += v;
                }
            }
        }
#pragma unroll
        for (int i = 0; i < 4; ++i) {
#pragma unroll
            for (int r = 0; r < 4; ++r) {
                float s = rp[i][r];
                s += __shfl_xor(s, 1);
                s += __shfl_xor(s, 2);
                s += __shfl_xor(s, 4);
                s += __shfl_xor(s, 8);
                if ((lane & 15) == 0) {
                    int row = bm + wm * 64 + i * 16 + (lane >> 4) * 4 + r;
                    atomicAdd(&lb[row], s);
                }
            }
        }
    }
}

// Atomic-free column-sum partials: wpart[s][b][j] = sum_{r in strip s} P[b][r][j]/l[b][r]
// grid (64, 8), 256 threads; strip = 32 rows; thread owns 8 consecutive cols.
__global__ __launch_bounds__(256) void k_w2(const bf16* __restrict__ P,
                                            const float* __restrict__ l,
                                            float* __restrict__ wpart) {
    const int tid = threadIdx.x;
    const int s = blockIdx.x, b = blockIdx.y;
    const int r0 = s * 32;
    const bf16* Pb = P + (size_t)b * N_ * N_ + (size_t)r0 * N_;
    const float* lb = l + b * N_ + r0;
    const int j0 = tid * 8;
    float acc8[8] = {0.f, 0.f, 0.f, 0.f, 0.f, 0.f, 0.f, 0.f};
#pragma unroll 4
    for (int r = 0; r < 32; ++r) {
        float rr = 1.0f / lb[r];
        bf16x8 v = *(const bf16x8*)&Pb[(size_t)r * N_ + j0];
#pragma unroll
        for (int e = 0; e < 8; ++e) acc8[e] += rr * (float)v[e];
    }
    float* wp = wpart + ((size_t)s * 8 + b) * N_;
#pragma unroll
    for (int e = 0; e < 8; ++e) wp[j0 + e] = acc8[e];
}

// w[b][j] = sum_s wpart[s][b][j]
__global__ void k_wsum(const float* __restrict__ wpart, float* __restrict__ w) {
    int gt = blockIdx.x * 256 + threadIdx.x;    // 16384 threads
    int b = gt >> 11, j = gt & 2047;
    float s = 0.f;
#pragma unroll
    for (int k = 0; k < 64; ++k) s += wpart[((size_t)k * 8 + b) * N_ + j];
    w[b * N_ + j] = s;
}

// gpacc[b][c] += sum_{j in 64-row slab} (w[b][j]+1) * nodes_bf[b][j][c]
__global__ void k_gp(const bf16* __restrict__ nodes_bf, const float* __restrict__ w,
                     float* __restrict__ gpacc) {
    const int tid = threadIdx.x;
    const int b = blockIdx.y;
    const int j0 = blockIdx.x * 64;
    const int cc = (tid & 63) * 8, jr = tid >> 6;
    const bf16* nb = nodes_bf + (size_t)b * N_ * C_;
    const float* wb = w + b * N_;
    float acc8[8] = {0.f, 0.f, 0.f, 0.f, 0.f, 0.f, 0.f, 0.f};
    for (int j = jr; j < 64; j += 4) {
        float wj = wb[j0 + j] + 1.0f;
        bf16x8 nv = *(const bf16x8*)&nb[(size_t)(j0 + j) * C_ + cc];
#pragma unroll
        for (int e = 0; e < 8; ++e) acc8[e] += wj * (float)nv[e];
    }
#pragma unroll
    for (int e = 0; e < 8; ++e) atomicAdd(&gpacc[b * C_ + cc + e], acc8[e]);
}

__global__ void k_fin(const float* __restrict__ gpacc, float* __restrict__ out) {
    int gt = blockIdx.x * 256 + threadIdx.x;
    int b = gt >> 9, c = gt & 511;
    out[b * 2 * C_ + C_ + c] = gpacc[b * C_ + c] * (1.0f / N_);
}

extern "C" void kernel_launch(void* const* d_in, const int* in_sizes, int n_in,
                              void* d_out, int out_size, void* d_ws, size_t ws_size,
                              hipStream_t stream) {
    const float* vd_s  = (const float*)d_in[0];
    const float* nodes = (const float*)d_in[1];
    const float* W1    = (const float*)d_in[2];
    const float* b1    = (const float*)d_in[3];
    const float* W2    = (const float*)d_in[4];
    // d_in[5] (b2) adds a row-constant to adj -> cancels in row-softmax -> unused
    float* out = (float*)d_out;

    char* ws = (char*)d_ws;
    bf16*  nodes_bf = (bf16*)(ws);                                   // 16 MB
    bf16*  H2       = (bf16*)(ws + ((size_t)16 << 20));              // 16 MB
    float* wpart    = (float*)(ws + ((size_t)16 << 20));             // 4 MB, overlays H2
                                                                     // (H2 dead after P-GEMM)
    bf16*  P        = (bf16*)(ws + ((size_t)32 << 20));              // 64 MB
    bf16*  W1t      = (bf16*)(ws + ((size_t)96 << 20));              // 512 KB
    bf16*  W2t      = (bf16*)(ws + ((size_t)96 << 20) + (512u << 10));
    bf16*  Gt       = (bf16*)(ws + ((size_t)96 << 20) + (1024u << 10));
    char*  fbase    = ws + ((size_t)96 << 20) + (1536u << 10);
    float* q        = (float*)(fbase);                     // 4 KB
    float* w        = (float*)(fbase + 4096);              // 64 KB (plain writes)
    float* gpacc    = (float*)(fbase + 4096 + 65536);      // 16 KB (atomics)
    float* l        = (float*)(fbase + 4096 + 65536 + 16384);  // 64 KB (atomics)

    // zero q + w + gpacc + l (contiguous 148 KB)
    (void)hipMemsetAsync(q, 0, 4096 + 65536 + 16384 + 65536, stream);

    k_prep<<<2592, 256, 0, stream>>>(vd_s, nodes, W1, W2, b1,
                                     out, nodes_bf, W1t, W2t, q);

    // Gt[c][k] = sum_m W2t[c][m]*W1t[k][m]   (M=N=K=512)
    gemm_nt<false><<<dim3(4, 4, 1), 256, 0, stream>>>(
        W2t, 0, W1t, 0, nullptr, nullptr, Gt, 0, C_, C_);
    // H2[b] = nodes_bf[b] @ Gt^T + q[col]   (M=2048, N=512, K=512)
    gemm_nt<false><<<dim3(16, 4, 8), 256, 0, stream>>>(
        nodes_bf, (size_t)N_ * C_, Gt, 0, q, nullptr,
        H2, (size_t)N_ * C_, C_, C_);
    // P[b] = exp(H2[b] @ nodes_bf[b]^T), l[b][row] += row sums  (M=N=2048, K=512)
    gemm_nt<true><<<dim3(16, 16, 8), 256, 0, stream>>>(
        H2, (size_t)N_ * C_, nodes_bf, (size_t)N_ * C_, nullptr, l,
        P, (size_t)N_ * N_, N_, C_);

    k_w2<<<dim3(64, 8), 256, 0, stream>>>(P, l, wpart);
    k_wsum<<<64, 256, 0, stream>>>(wpart, w);
    k_gp<<<dim3(32, 8), 256, 0, stream>>>(nodes_bf, w, gpacc);
    k_fin<<<16, 256, 0, stream>>>(gpacc, out);
}

// Round 8
// 168.357 us; speedup vs baseline: 1.2896x; 1.0008x over previous
//
#include <hip/hip_runtime.h>

typedef __bf16 bf16;
typedef __bf16 bf16x8 __attribute__((ext_vector_type(8), aligned(16)));
typedef float  f32x4  __attribute__((ext_vector_type(4)));

#define B_ 8
#define T_ 16
#define N_ 2048
#define C_ 512

// ---- helpers ----
__device__ inline bf16x8 load8_f32(const float* p) {
    float4 a = *(const float4*)p;
    float4 b = *(const float4*)(p + 4);
    bf16x8 r;
    r[0] = (bf16)a.x; r[1] = (bf16)a.y; r[2] = (bf16)a.z; r[3] = (bf16)a.w;
    r[4] = (bf16)b.x; r[5] = (bf16)b.y; r[6] = (bf16)b.z; r[7] = (bf16)b.w;
    return r;
}

__device__ inline void gload_lds16(const bf16* g, bf16* l) {
    __builtin_amdgcn_global_load_lds(
        (const __attribute__((address_space(1))) void*)g,
        (__attribute__((address_space(3))) void*)l, 16, 0, 0);
}

// One merged prep kernel:
//   [0,2048):    nodes fp32 -> bf16
//   [2048,2064): out_scene = mean_t vd_s
//   [2064,2320): W1t = W1^T (bf16)
//   [2320,2576): W2t = W2^T (bf16)
//   [2576,2578): q[c] = sum_k b1[k]*W2[k][c]  (plain store, no atomics)
__global__ __launch_bounds__(256) void k_prep(
    const float* __restrict__ vd_s, const float* __restrict__ nodes,
    const float* __restrict__ W1, const float* __restrict__ W2,
    const float* __restrict__ b1,
    float* __restrict__ out, bf16* __restrict__ nodes_bf,
    bf16* __restrict__ W1t, bf16* __restrict__ W2t, float* __restrict__ q) {
    __shared__ float sh[32 * 33];
    const int bx = blockIdx.x, tid = threadIdx.x;
    if (bx < 2048) {
        size_t i = ((size_t)bx * 256 + tid) * 16;
        *(bf16x8*)(nodes_bf + i)     = load8_f32(nodes + i);
        *(bf16x8*)(nodes_bf + i + 8) = load8_f32(nodes + i + 8);
    } else if (bx < 2064) {
        int gt = (bx - 2048) * 256 + tid;
        int b = gt >> 9, c = gt & 511;
        float s = 0.f;
#pragma unroll
        for (int t = 0; t < T_; ++t) s += vd_s[(size_t)b * T_ * C_ + t * C_ + c];
        out[b * 2 * C_ + c] = s * (1.0f / T_);
    } else if (bx < 2576) {
        const float* W = (bx < 2320) ? W1 : W2;
        bf16* Wt = (bx < 2320) ? W1t : W2t;
        int idx = (bx < 2320) ? bx - 2064 : bx - 2320;
        int bxx = (idx & 15) * 32, byy = (idx >> 4) * 32;
        int tx = tid & 31, ty = tid >> 5;
#pragma unroll
        for (int r = 0; r < 32; r += 8)
            sh[(ty + r) * 33 + tx] = W[(size_t)(byy + ty + r) * C_ + bxx + tx];
        __syncthreads();
#pragma unroll
        for (int r = 0; r < 32; r += 8)
            Wt[(size_t)(bxx + ty + r) * C_ + byy + tx] = (bf16)sh[tx * 33 + ty + r];
    } else {
        int c = (bx - 2576) * 256 + tid;       // [0,512)
        float s = 0.f;
#pragma unroll 4
        for (int k = 0; k < C_; ++k) s += b1[k] * W2[(size_t)k * C_ + c];
        q[c] = s;
    }
}

// 128x128-tile NT GEMM (round-3 measured structure).
// EXPOUT: C = exp(min(acc,30)).  else: C = acc + bias[n].
template <bool EXPOUT>
__global__ __launch_bounds__(256) void gemm_nt(
    const bf16* __restrict__ A, size_t strideA,
    const bf16* __restrict__ Bm, size_t strideB,
    const float* __restrict__ bias,
    bf16* __restrict__ C, size_t strideC,
    int N, int K) {
    __shared__ __attribute__((aligned(16))) bf16 lA[128 * 64];
    __shared__ __attribute__((aligned(16))) bf16 lB[128 * 64];
    const int tid = threadIdx.x;
    const int lane = tid & 63, w = tid >> 6;
    const int wm = w >> 1, wn = w & 1;
    const int z = blockIdx.z;
    const int bm = blockIdx.x * 128, bn = blockIdx.y * 128;
    const bf16* Ab = A + (size_t)z * strideA;
    const bf16* Bb = Bm + (size_t)z * strideB;

    f32x4 acc[4][4];
#pragma unroll
    for (int i = 0; i < 4; ++i)
#pragma unroll
        for (int j = 0; j < 4; ++j) acc[i][j] = f32x4{0.f, 0.f, 0.f, 0.f};

    const int nkt = K >> 6;
    for (int kt = 0; kt < nkt; ++kt) {
#pragma unroll
        for (int c = 0; c < 4; ++c) {
            int ca = c * 256 + tid;
            int row = ca >> 3;
            int qd = (ca & 7) ^ (row & 7);
            gload_lds16(Ab + (size_t)(bm + row) * K + kt * 64 + qd * 8,
                        lA + c * 2048 + w * 512);
            gload_lds16(Bb + (size_t)(bn + row) * K + kt * 64 + qd * 8,
                        lB + c * 2048 + w * 512);
        }
        __syncthreads();

        bf16x8 af[2][4], bfr[2][4];
#pragma unroll
        for (int ks = 0; ks < 2; ++ks) {
            int y = ks * 4 + (lane >> 4);
#pragma unroll
            for (int i = 0; i < 4; ++i) {
                int ra = wm * 64 + i * 16 + (lane & 15);
                int rb = wn * 64 + i * 16 + (lane & 15);
                af[ks][i]  = *(const bf16x8*)&lA[ra * 64 + ((y ^ (ra & 7)) * 8)];
                bfr[ks][i] = *(const bf16x8*)&lB[rb * 64 + ((y ^ (rb & 7)) * 8)];
            }
        }
#pragma unroll
        for (int ks = 0; ks < 2; ++ks)
#pragma unroll
            for (int i = 0; i < 4; ++i)
#pragma unroll
                for (int j = 0; j < 4; ++j)
                    acc[i][j] = __builtin_amdgcn_mfma_f32_16x16x32_bf16(
                        af[ks][i], bfr[ks][j], acc[i][j], 0, 0, 0);
        __syncthreads();
    }

    bf16* Cb = C + (size_t)z * strideC;
#pragma unroll
    for (int i = 0; i < 4; ++i) {
#pragma unroll
        for (int j = 0; j < 4; ++j) {
            int col = bn + wn * 64 + j * 16 + (lane & 15);
            float bv = (!EXPOUT && bias) ? bias[col] : 0.f;
#pragma unroll
            for (int r = 0; r < 4; ++r) {
                int row = bm + wm * 64 + i * 16 + (lane >> 4) * 4 + r;
                float v = acc[i][j][r];
                if (EXPOUT) v = __expf(fminf(v, 30.f));
                else        v = v + bv;
                Cb[(size_t)row * N + col] = (bf16)v;
            }
        }
    }
}

// Single-read softmax column-sums: block (s,b) owns 8 rows x all 2048 cols.
// Pass 1: exact row sums l (LDS + shfl within 32-lane halves).
// Pass 2: reuse register-held P chunks for sum_i P_ij / l_i.
// Plain-store partials wpart[b][s][j]. No atomics. grid (256,8), 256 thr.
__global__ __launch_bounds__(256) void k_w2(const bf16* __restrict__ P,
                                            float* __restrict__ wpart) {
    __shared__ float rp[8 * 256];
    __shared__ float ri[8];
    const int tid = threadIdx.x;
    const int s = blockIdx.x, b = blockIdx.y;
    const bf16* Pb = P + (size_t)b * N_ * N_ + (size_t)s * 8 * N_;
    const int j0 = tid * 8;
    bf16x8 v[8];
#pragma unroll
    for (int r = 0; r < 8; ++r) {
        v[r] = *(const bf16x8*)&Pb[(size_t)r * N_ + j0];
        float t = 0.f;
#pragma unroll
        for (int e = 0; e < 8; ++e) t += (float)v[r][e];
        rp[r * 256 + tid] = t;
    }
    __syncthreads();
    {
        int row = tid >> 5, seg = tid & 31;    // 8 rows x 32 segs
        float t = 0.f;
#pragma unroll
        for (int k = 0; k < 8; ++k) t += rp[row * 256 + seg + 32 * k];
#pragma unroll
        for (int m = 16; m; m >>= 1) t += __shfl_xor(t, m);
        if (seg == 0) ri[row] = 1.0f / t;
    }
    __syncthreads();
    float acc8[8] = {0.f, 0.f, 0.f, 0.f, 0.f, 0.f, 0.f, 0.f};
#pragma unroll
    for (int r = 0; r < 8; ++r) {
        float rr = ri[r];
#pragma unroll
        for (int e = 0; e < 8; ++e) acc8[e] += rr * (float)v[r][e];
    }
    float* wp = wpart + ((size_t)b * 256 + s) * (size_t)N_;
#pragma unroll
    for (int e = 0; e < 8; ++e) wp[j0 + e] = acc8[e];
}

// Block (slab,b): w[j] = 1 + sum_s wpart[b][s][j] for its 64 j's (in LDS),
// then gppart[slab][b][c] = sum_j w[j]*nodes_bf[b][j][c]. No atomics.
__global__ __launch_bounds__(256) void k_gp(const bf16* __restrict__ nodes_bf,
                                            const float* __restrict__ wpart,
                                            float* __restrict__ gppart) {
    __shared__ float wred[4][64];
    __shared__ float wsh[64];
    __shared__ float gred[4][512];
    const int tid = threadIdx.x;
    const int slab = blockIdx.x, b = blockIdx.y;
    const int jj = tid & 63, sg = tid >> 6;
    float wacc = 0.f;
    for (int s = sg; s < 256; s += 4)
        wacc += wpart[((size_t)b * 256 + s) * N_ + slab * 64 + jj];
    wred[sg][jj] = wacc;
    __syncthreads();
    if (tid < 64)
        wsh[tid] = wred[0][tid] + wred[1][tid] + wred[2][tid] + wred[3][tid] + 1.0f;
    __syncthreads();
    const int j0 = slab * 64;
    const int cc = (tid & 63) * 8, jr = tid >> 6;
    const bf16* nb = nodes_bf + (size_t)b * N_ * C_;
    float acc8[8] = {0.f, 0.f, 0.f, 0.f, 0.f, 0.f, 0.f, 0.f};
    for (int j = jr; j < 64; j += 4) {
        float wj = wsh[j];
        bf16x8 nv = *(const bf16x8*)&nb[(size_t)(j0 + j) * C_ + cc];
#pragma unroll
        for (int e = 0; e < 8; ++e) acc8[e] += wj * (float)nv[e];
    }
#pragma unroll
    for (int e = 0; e < 8; ++e) gred[jr][cc + e] = acc8[e];
    __syncthreads();
    if (tid < 64) {
#pragma unroll
        for (int e = 0; e < 8; ++e) {
            int c = tid * 8 + e;
            gppart[((size_t)slab * 8 + b) * C_ + c] =
                gred[0][c] + gred[1][c] + gred[2][c] + gred[3][c];
        }
    }
}

// out[b][512+c] = (1/N) * sum_slab gppart[slab][b][c]
__global__ void k_fin(const float* __restrict__ gppart, float* __restrict__ out) {
    int gt = blockIdx.x * 256 + threadIdx.x;   // 4096 threads
    int b = gt >> 9, c = gt & 511;
    float s = 0.f;
#pragma unroll
    for (int k = 0; k < 32; ++k) s += gppart[((size_t)k * 8 + b) * C_ + c];
    out[b * 2 * C_ + C_ + c] = s * (1.0f / N_);
}

extern "C" void kernel_launch(void* const* d_in, const int* in_sizes, int n_in,
                              void* d_out, int out_size, void* d_ws, size_t ws_size,
                              hipStream_t stream) {
    const float* vd_s  = (const float*)d_in[0];
    const float* nodes = (const float*)d_in[1];
    const float* W1    = (const float*)d_in[2];
    const float* b1    = (const float*)d_in[3];
    const float* W2    = (const float*)d_in[4];
    // d_in[5] (b2) adds a row-constant to adj -> cancels in row-softmax -> unused
    float* out = (float*)d_out;

    char* ws = (char*)d_ws;
    bf16*  nodes_bf = (bf16*)(ws);                                   // 16 MB
    bf16*  H2       = (bf16*)(ws + ((size_t)16 << 20));              // 16 MB
    float* wpart    = (float*)(ws + ((size_t)16 << 20));             // 16 MB, overlays H2
                                                                     // (H2 dead after P-GEMM)
    bf16*  P        = (bf16*)(ws + ((size_t)32 << 20));              // 64 MB
    bf16*  W1t      = (bf16*)(ws + ((size_t)96 << 20));              // 512 KB
    bf16*  W2t      = (bf16*)(ws + ((size_t)96 << 20) + (512u << 10));
    bf16*  Gt       = (bf16*)(ws + ((size_t)96 << 20) + (1024u << 10));
    char*  fbase    = ws + ((size_t)96 << 20) + (1536u << 10);
    float* q        = (float*)(fbase);                     // 2 KB (plain stores)
    float* gppart   = (float*)(fbase + 4096);              // 512 KB (plain stores)

    k_prep<<<2578, 256, 0, stream>>>(vd_s, nodes, W1, W2, b1,
                                     out, nodes_bf, W1t, W2t, q);

    // Gt[c][k] = sum_m W2t[c][m]*W1t[k][m]   (M=N=K=512)
    gemm_nt<false><<<dim3(4, 4, 1), 256, 0, stream>>>(
        W2t, 0, W1t, 0, nullptr, Gt, 0, C_, C_);
    // H2[b] = nodes_bf[b] @ Gt^T + q[col]   (M=2048, N=512, K=512)
    gemm_nt<false><<<dim3(16, 4, 8), 256, 0, stream>>>(
        nodes_bf, (size_t)N_ * C_, Gt, 0, q,
        H2, (size_t)N_ * C_, C_, C_);
    // P[b] = exp(H2[b] @ nodes_bf[b]^T)   (M=N=2048, K=512)
    gemm_nt<true><<<dim3(16, 16, 8), 256, 0, stream>>>(
        H2, (size_t)N_ * C_, nodes_bf, (size_t)N_ * C_, nullptr,
        P, (size_t)N_ * N_, N_, C_);

    k_w2<<<dim3(256, 8), 256, 0, stream>>>(P, wpart);
    k_gp<<<dim3(32, 8), 256, 0, stream>>>(nodes_bf, wpart, gppart);
    k_fin<<<16, 256, 0, stream>>>(gppart, out);
}

// Round 9
// 125.986 us; speedup vs baseline: 1.7233x; 1.3363x over previous
//
#include <hip/hip_runtime.h>

typedef __bf16 bf16;
typedef __bf16 bf16x8 __attribute__((ext_vector_type(8), aligned(16)));
typedef float  f32x4  __attribute__((ext_vector_type(4)));

#define B_ 8
#define T_ 16
#define N_ 2048
#define C_ 512

// ---- helpers ----
__device__ inline bf16x8 load8_f32(const float* p) {
    float4 a = *(const float4*)p;
    float4 b = *(const float4*)(p + 4);
    bf16x8 r;
    r[0] = (bf16)a.x; r[1] = (bf16)a.y; r[2] = (bf16)a.z; r[3] = (bf16)a.w;
    r[4] = (bf16)b.x; r[5] = (bf16)b.y; r[6] = (bf16)b.z; r[7] = (bf16)b.w;
    return r;
}

__device__ inline void gload_lds16(const bf16* g, bf16* l) {
    __builtin_amdgcn_global_load_lds(
        (const __attribute__((address_space(1))) void*)g,
        (__attribute__((address_space(3))) void*)l, 16, 0, 0);
}

// Merged prep kernel (q removed -> no straggler blocks):
//   [0,2048):    nodes fp32 -> bf16
//   [2048,2064): out_scene = mean_t vd_s
//   [2064,2320): W1t = W1^T (bf16)
//   [2320,2576): W2t = W2^T (bf16)
__global__ __launch_bounds__(256) void k_prep(
    const float* __restrict__ vd_s, const float* __restrict__ nodes,
    const float* __restrict__ W1, const float* __restrict__ W2,
    float* __restrict__ out, bf16* __restrict__ nodes_bf,
    bf16* __restrict__ W1t, bf16* __restrict__ W2t) {
    __shared__ float sh[32 * 33];
    const int bx = blockIdx.x, tid = threadIdx.x;
    if (bx < 2048) {
        size_t i = ((size_t)bx * 256 + tid) * 16;
        *(bf16x8*)(nodes_bf + i)     = load8_f32(nodes + i);
        *(bf16x8*)(nodes_bf + i + 8) = load8_f32(nodes + i + 8);
    } else if (bx < 2064) {
        int gt = (bx - 2048) * 256 + tid;
        int b = gt >> 9, c = gt & 511;
        float s = 0.f;
#pragma unroll
        for (int t = 0; t < T_; ++t) s += vd_s[(size_t)b * T_ * C_ + t * C_ + c];
        out[b * 2 * C_ + c] = s * (1.0f / T_);
    } else {
        const float* W = (bx < 2320) ? W1 : W2;
        bf16* Wt = (bx < 2320) ? W1t : W2t;
        int idx = (bx < 2320) ? bx - 2064 : bx - 2320;
        int bxx = (idx & 15) * 32, byy = (idx >> 4) * 32;
        int tx = tid & 31, ty = tid >> 5;
#pragma unroll
        for (int r = 0; r < 32; r += 8)
            sh[(ty + r) * 33 + tx] = W[(size_t)(byy + ty + r) * C_ + bxx + tx];
        __syncthreads();
#pragma unroll
        for (int r = 0; r < 32; r += 8)
            Wt[(size_t)(bxx + ty + r) * C_ + byy + tx] = (bf16)sh[tx * 33 + ty + r];
    }
}

// q[c] = sum_k b1[k] * W2t[c][k]   one wave per c (coalesced bf16x8), ~1-2 us
__global__ void k_q(const float* __restrict__ b1, const bf16* __restrict__ W2t,
                    float* __restrict__ q) {
    int wid = threadIdx.x >> 6, lane = threadIdx.x & 63;
    int c = blockIdx.x * 4 + wid;
    bf16x8 v8 = *(const bf16x8*)(W2t + (size_t)c * C_ + lane * 8);
    float s = 0.f;
#pragma unroll
    for (int i = 0; i < 8; ++i) s += (float)v8[i] * b1[lane * 8 + i];
#pragma unroll
    for (int m = 32; m; m >>= 1) s += __shfl_xor(s, m);
    if (lane == 0) q[c] = s;
}

// 128x128-tile NT GEMM (round-3 measured structure).
// EXPOUT: C = exp(min(acc,30)).  else: C = acc + bias[n].
template <bool EXPOUT>
__global__ __launch_bounds__(256) void gemm_nt(
    const bf16* __restrict__ A, size_t strideA,
    const bf16* __restrict__ Bm, size_t strideB,
    const float* __restrict__ bias,
    bf16* __restrict__ C, size_t strideC,
    int N, int K) {
    __shared__ __attribute__((aligned(16))) bf16 lA[128 * 64];
    __shared__ __attribute__((aligned(16))) bf16 lB[128 * 64];
    const int tid = threadIdx.x;
    const int lane = tid & 63, w = tid >> 6;
    const int wm = w >> 1, wn = w & 1;
    const int z = blockIdx.z;
    const int bm = blockIdx.x * 128, bn = blockIdx.y * 128;
    const bf16* Ab = A + (size_t)z * strideA;
    const bf16* Bb = Bm + (size_t)z * strideB;

    f32x4 acc[4][4];
#pragma unroll
    for (int i = 0; i < 4; ++i)
#pragma unroll
        for (int j = 0; j < 4; ++j) acc[i][j] = f32x4{0.f, 0.f, 0.f, 0.f};

    const int nkt = K >> 6;
    for (int kt = 0; kt < nkt; ++kt) {
#pragma unroll
        for (int c = 0; c < 4; ++c) {
            int ca = c * 256 + tid;
            int row = ca >> 3;
            int qd = (ca & 7) ^ (row & 7);
            gload_lds16(Ab + (size_t)(bm + row) * K + kt * 64 + qd * 8,
                        lA + c * 2048 + w * 512);
            gload_lds16(Bb + (size_t)(bn + row) * K + kt * 64 + qd * 8,
                        lB + c * 2048 + w * 512);
        }
        __syncthreads();

        bf16x8 af[2][4], bfr[2][4];
#pragma unroll
        for (int ks = 0; ks < 2; ++ks) {
            int y = ks * 4 + (lane >> 4);
#pragma unroll
            for (int i = 0; i < 4; ++i) {
                int ra = wm * 64 + i * 16 + (lane & 15);
                int rb = wn * 64 + i * 16 + (lane & 15);
                af[ks][i]  = *(const bf16x8*)&lA[ra * 64 + ((y ^ (ra & 7)) * 8)];
                bfr[ks][i] = *(const bf16x8*)&lB[rb * 64 + ((y ^ (rb & 7)) * 8)];
            }
        }
#pragma unroll
        for (int ks = 0; ks < 2; ++ks)
#pragma unroll
            for (int i = 0; i < 4; ++i)
#pragma unroll
                for (int j = 0; j < 4; ++j)
                    acc[i][j] = __builtin_amdgcn_mfma_f32_16x16x32_bf16(
                        af[ks][i], bfr[ks][j], acc[i][j], 0, 0, 0);
        __syncthreads();
    }

    bf16* Cb = C + (size_t)z * strideC;
#pragma unroll
    for (int i = 0; i < 4; ++i) {
#pragma unroll
        for (int j = 0; j < 4; ++j) {
            int col = bn + wn * 64 + j * 16 + (lane & 15);
            float bv = (!EXPOUT && bias) ? bias[col] : 0.f;
#pragma unroll
            for (int r = 0; r < 4; ++r) {
                int row = bm + wm * 64 + i * 16 + (lane >> 4) * 4 + r;
                float v = acc[i][j][r];
                if (EXPOUT) v = __expf(fminf(v, 30.f));
                else        v = v + bv;
                Cb[(size_t)row * N + col] = (bf16)v;
            }
        }
    }
}

// Single-read softmax column-sums: block (s,b) owns 16 rows x all 2048 cols.
// Pass 1: exact row sums l (LDS + 16-lane shfl). Pass 2: registers reused for
// sum_i P_ij / l_i. Plain-store partials wpart[b][s][j]. grid (128,8), 256 thr.
__global__ __launch_bounds__(256) void k_w2(const bf16* __restrict__ P,
                                            float* __restrict__ wpart) {
    __shared__ float rp[16 * 256];   // 16 KB
    __shared__ float ri[16];
    const int tid = threadIdx.x;
    const int s = blockIdx.x, b = blockIdx.y;
    const bf16* Pb = P + (size_t)b * N_ * N_ + (size_t)s * 16 * N_;
    const int j0 = tid * 8;
    bf16x8 v[16];
#pragma unroll
    for (int r = 0; r < 16; ++r) {
        v[r] = *(const bf16x8*)&Pb[(size_t)r * N_ + j0];
        float t = 0.f;
#pragma unroll
        for (int e = 0; e < 8; ++e) t += (float)v[r][e];
        rp[r * 256 + tid] = t;
    }
    __syncthreads();
    {
        int row = tid >> 4, seg = tid & 15;    // 16 rows x 16 segs
        float t = 0.f;
#pragma unroll
        for (int k = 0; k < 16; ++k) t += rp[row * 256 + seg + 16 * k];
#pragma unroll
        for (int m = 8; m; m >>= 1) t += __shfl_xor(t, m);
        if (seg == 0) ri[row] = 1.0f / t;
    }
    __syncthreads();
    float acc8[8] = {0.f, 0.f, 0.f, 0.f, 0.f, 0.f, 0.f, 0.f};
#pragma unroll
    for (int r = 0; r < 16; ++r) {
        float rr = ri[r];
#pragma unroll
        for (int e = 0; e < 8; ++e) acc8[e] += rr * (float)v[r][e];
    }
    float* wp = wpart + ((size_t)b * 128 + s) * (size_t)N_;
#pragma unroll
    for (int e = 0; e < 8; ++e) wp[j0 + e] = acc8[e];
}

// Block (slab,b): w[j] = 1 + sum_s wpart[b][s][j] for its 64 j's (in LDS),
// then gppart[slab][b][c] = sum_j w[j]*nodes_bf[b][j][c]. No atomics.
__global__ __launch_bounds__(256) void k_gp(const bf16* __restrict__ nodes_bf,
                                            const float* __restrict__ wpart,
                                            float* __restrict__ gppart) {
    __shared__ float wred[4][64];
    __shared__ float wsh[64];
    __shared__ float gred[4][512];
    const int tid = threadIdx.x;
    const int slab = blockIdx.x, b = blockIdx.y;
    const int jj = tid & 63, sg = tid >> 6;
    float wacc = 0.f;
    for (int s = sg; s < 128; s += 4)
        wacc += wpart[((size_t)b * 128 + s) * N_ + slab * 64 + jj];
    wred[sg][jj] = wacc;
    __syncthreads();
    if (tid < 64)
        wsh[tid] = wred[0][tid] + wred[1][tid] + wred[2][tid] + wred[3][tid] + 1.0f;
    __syncthreads();
    const int j0 = slab * 64;
    const int cc = (tid & 63) * 8, jr = tid >> 6;
    const bf16* nb = nodes_bf + (size_t)b * N_ * C_;
    float acc8[8] = {0.f, 0.f, 0.f, 0.f, 0.f, 0.f, 0.f, 0.f};
    for (int j = jr; j < 64; j += 4) {
        float wj = wsh[j];
        bf16x8 nv = *(const bf16x8*)&nb[(size_t)(j0 + j) * C_ + cc];
#pragma unroll
        for (int e = 0; e < 8; ++e) acc8[e] += wj * (float)nv[e];
    }
#pragma unroll
    for (int e = 0; e < 8; ++e) gred[jr][cc + e] = acc8[e];
    __syncthreads();
    if (tid < 64) {
#pragma unroll
        for (int e = 0; e < 8; ++e) {
            int c = tid * 8 + e;
            gppart[((size_t)slab * 8 + b) * C_ + c] =
                gred[0][c] + gred[1][c] + gred[2][c] + gred[3][c];
        }
    }
}

// out[b][512+c] = (1/N) * sum_slab gppart[slab][b][c]
__global__ void k_fin(const float* __restrict__ gppart, float* __restrict__ out) {
    int gt = blockIdx.x * 256 + threadIdx.x;   // 4096 threads
    int b = gt >> 9, c = gt & 511;
    float s = 0.f;
#pragma unroll
    for (int k = 0; k < 32; ++k) s += gppart[((size_t)k * 8 + b) * C_ + c];
    out[b * 2 * C_ + C_ + c] = s * (1.0f / N_);
}

extern "C" void kernel_launch(void* const* d_in, const int* in_sizes, int n_in,
                              void* d_out, int out_size, void* d_ws, size_t ws_size,
                              hipStream_t stream) {
    const float* vd_s  = (const float*)d_in[0];
    const float* nodes = (const float*)d_in[1];
    const float* W1    = (const float*)d_in[2];
    const float* b1    = (const float*)d_in[3];
    const float* W2    = (const float*)d_in[4];
    // d_in[5] (b2) adds a row-constant to adj -> cancels in row-softmax -> unused
    float* out = (float*)d_out;

    char* ws = (char*)d_ws;
    bf16*  nodes_bf = (bf16*)(ws);                                   // 16 MB
    bf16*  H2       = (bf16*)(ws + ((size_t)16 << 20));              // 16 MB
    float* wpart    = (float*)(ws + ((size_t)16 << 20));             // 8 MB, overlays H2
                                                                     // (H2 dead after P-GEMM)
    bf16*  P        = (bf16*)(ws + ((size_t)32 << 20));              // 64 MB
    bf16*  W1t      = (bf16*)(ws + ((size_t)96 << 20));              // 512 KB
    bf16*  W2t      = (bf16*)(ws + ((size_t)96 << 20) + (512u << 10));
    bf16*  Gt       = (bf16*)(ws + ((size_t)96 << 20) + (1024u << 10));
    char*  fbase    = ws + ((size_t)96 << 20) + (1536u << 10);
    float* q        = (float*)(fbase);                     // 2 KB (plain stores)
    float* gppart   = (float*)(fbase + 4096);              // 512 KB (plain stores)

    k_prep<<<2576, 256, 0, stream>>>(vd_s, nodes, W1, W2,
                                     out, nodes_bf, W1t, W2t);
    k_q<<<128, 256, 0, stream>>>(b1, W2t, q);

    // Gt[c][k] = sum_m W2t[c][m]*W1t[k][m]   (M=N=K=512)
    gemm_nt<false><<<dim3(4, 4, 1), 256, 0, stream>>>(
        W2t, 0, W1t, 0, nullptr, Gt, 0, C_, C_);
    // H2[b] = nodes_bf[b] @ Gt^T + q[col]   (M=2048, N=512, K=512)
    gemm_nt<false><<<dim3(16, 4, 8), 256, 0, stream>>>(
        nodes_bf, (size_t)N_ * C_, Gt, 0, q,
        H2, (size_t)N_ * C_, C_, C_);
    // P[b] = exp(H2[b] @ nodes_bf[b]^T)   (M=N=2048, K=512)
    gemm_nt<true><<<dim3(16, 16, 8), 256, 0, stream>>>(
        H2, (size_t)N_ * C_, nodes_bf, (size_t)N_ * C_, nullptr,
        P, (size_t)N_ * N_, N_, C_);

    k_w2<<<dim3(128, 8), 256, 0, stream>>>(P, wpart);
    k_gp<<<dim3(32, 8), 256, 0, stream>>>(nodes_bf, wpart, gppart);
    k_fin<<<16, 256, 0, stream>>>(gppart, out);
}

// Round 10
// 115.381 us; speedup vs baseline: 1.8817x; 1.0919x over previous
//
#include <hip/hip_runtime.h>

typedef __bf16 bf16;
typedef __bf16 bf16x8 __attribute__((ext_vector_type(8), aligned(16)));
typedef float  f32x4  __attribute__((ext_vector_type(4)));

#define B_ 8
#define T_ 16
#define N_ 2048
#define C_ 512

// ---- helpers ----
__device__ inline bf16x8 load8_f32(const float* p) {
    float4 a = *(const float4*)p;
    float4 b = *(const float4*)(p + 4);
    bf16x8 r;
    r[0] = (bf16)a.x; r[1] = (bf16)a.y; r[2] = (bf16)a.z; r[3] = (bf16)a.w;
    r[4] = (bf16)b.x; r[5] = (bf16)b.y; r[6] = (bf16)b.z; r[7] = (bf16)b.w;
    return r;
}

__device__ inline void gload_lds16(const bf16* g, bf16* l) {
    __builtin_amdgcn_global_load_lds(
        (const __attribute__((address_space(1))) void*)g,
        (__attribute__((address_space(3))) void*)l, 16, 0, 0);
}

// Merged prep kernel:
//   [0,2048):    nodes fp32 -> bf16
//   [2048,2064): out_scene = mean_t vd_s
//   [2064,2320): W1t = W1^T   [2320,2576): W2t = W2^T
__global__ __launch_bounds__(256) void k_prep(
    const float* __restrict__ vd_s, const float* __restrict__ nodes,
    const float* __restrict__ W1, const float* __restrict__ W2,
    float* __restrict__ out, bf16* __restrict__ nodes_bf,
    bf16* __restrict__ W1t, bf16* __restrict__ W2t) {
    __shared__ float sh[32 * 33];
    const int bx = blockIdx.x, tid = threadIdx.x;
    if (bx < 2048) {
        size_t i = ((size_t)bx * 256 + tid) * 16;
        *(bf16x8*)(nodes_bf + i)     = load8_f32(nodes + i);
        *(bf16x8*)(nodes_bf + i + 8) = load8_f32(nodes + i + 8);
    } else if (bx < 2064) {
        int gt = (bx - 2048) * 256 + tid;
        int b = gt >> 9, c = gt & 511;
        float s = 0.f;
#pragma unroll
        for (int t = 0; t < T_; ++t) s += vd_s[(size_t)b * T_ * C_ + t * C_ + c];
        out[b * 2 * C_ + c] = s * (1.0f / T_);
    } else {
        const float* W = (bx < 2320) ? W1 : W2;
        bf16* Wt = (bx < 2320) ? W1t : W2t;
        int idx = (bx < 2320) ? bx - 2064 : bx - 2320;
        int bxx = (idx & 15) * 32, byy = (idx >> 4) * 32;
        int tx = tid & 31, ty = tid >> 5;
#pragma unroll
        for (int r = 0; r < 32; r += 8)
            sh[(ty + r) * 33 + tx] = W[(size_t)(byy + ty + r) * C_ + bxx + tx];
        __syncthreads();
#pragma unroll
        for (int r = 0; r < 32; r += 8)
            Wt[(size_t)(bxx + ty + r) * C_ + byy + tx] = (bf16)sh[tx * 33 + ty + r];
    }
}

// q[c] = sum_k b1[k] * W2t[c][k]   one wave per c
__global__ void k_q(const float* __restrict__ b1, const bf16* __restrict__ W2t,
                    float* __restrict__ q) {
    int wid = threadIdx.x >> 6, lane = threadIdx.x & 63;
    int c = blockIdx.x * 4 + wid;
    bf16x8 v8 = *(const bf16x8*)(W2t + (size_t)c * C_ + lane * 8);
    float s = 0.f;
#pragma unroll
    for (int i = 0; i < 8; ++i) s += (float)v8[i] * b1[lane * 8 + i];
#pragma unroll
    for (int m = 32; m; m >>= 1) s += __shfl_xor(s, m);
    if (lane == 0) q[c] = s;
}

// 128x128-tile NT GEMM (proven): C = A*B^T + bias.  Used for Gt, H2.
__global__ __launch_bounds__(256) void gemm_nt(
    const bf16* __restrict__ A, size_t strideA,
    const bf16* __restrict__ Bm, size_t strideB,
    const float* __restrict__ bias,
    bf16* __restrict__ C, size_t strideC,
    int N, int K) {
    __shared__ __attribute__((aligned(16))) bf16 lA[128 * 64];
    __shared__ __attribute__((aligned(16))) bf16 lB[128 * 64];
    const int tid = threadIdx.x;
    const int lane = tid & 63, w = tid >> 6;
    const int wm = w >> 1, wn = w & 1;
    const int z = blockIdx.z;
    const int bm = blockIdx.x * 128, bn = blockIdx.y * 128;
    const bf16* Ab = A + (size_t)z * strideA;
    const bf16* Bb = Bm + (size_t)z * strideB;

    f32x4 acc[4][4];
#pragma unroll
    for (int i = 0; i < 4; ++i)
#pragma unroll
        for (int j = 0; j < 4; ++j) acc[i][j] = f32x4{0.f, 0.f, 0.f, 0.f};

    const int nkt = K >> 6;
    for (int kt = 0; kt < nkt; ++kt) {
#pragma unroll
        for (int c = 0; c < 4; ++c) {
            int ca = c * 256 + tid;
            int row = ca >> 3;
            int qd = (ca & 7) ^ (row & 7);
            gload_lds16(Ab + (size_t)(bm + row) * K + kt * 64 + qd * 8,
                        lA + c * 2048 + w * 512);
            gload_lds16(Bb + (size_t)(bn + row) * K + kt * 64 + qd * 8,
                        lB + c * 2048 + w * 512);
        }
        __syncthreads();

        bf16x8 af[2][4], bfr[2][4];
#pragma unroll
        for (int ks = 0; ks < 2; ++ks) {
            int y = ks * 4 + (lane >> 4);
#pragma unroll
            for (int i = 0; i < 4; ++i) {
                int ra = wm * 64 + i * 16 + (lane & 15);
                int rb = wn * 64 + i * 16 + (lane & 15);
                af[ks][i]  = *(const bf16x8*)&lA[ra * 64 + ((y ^ (ra & 7)) * 8)];
                bfr[ks][i] = *(const bf16x8*)&lB[rb * 64 + ((y ^ (rb & 7)) * 8)];
            }
        }
#pragma unroll
        for (int ks = 0; ks < 2; ++ks)
#pragma unroll
            for (int i = 0; i < 4; ++i)
#pragma unroll
                for (int j = 0; j < 4; ++j)
                    acc[i][j] = __builtin_amdgcn_mfma_f32_16x16x32_bf16(
                        af[ks][i], bfr[ks][j], acc[i][j], 0, 0, 0);
        __syncthreads();
    }

    bf16* Cb = C + (size_t)z * strideC;
#pragma unroll
    for (int i = 0; i < 4; ++i) {
#pragma unroll
        for (int j = 0; j < 4; ++j) {
            int col = bn + wn * 64 + j * 16 + (lane & 15);
            float bv = bias ? bias[col] : 0.f;
#pragma unroll
            for (int r = 0; r < 4; ++r) {
                int row = bm + wm * 64 + i * 16 + (lane >> 4) * 4 + r;
                Cb[(size_t)row * N + col] = (bf16)(acc[i][j][r] + bv);
            }
        }
    }
}

// ---- P-GEMM: 256^2 tile, m201-cadence port (per-phase half-tile staging,
// counted vmcnt(4)/K-tile, B-frags cached, 4 quadrant phases x 16 MFMA). ----
// Fixed geometry: M=N=2048, K=512 (8 K-tiles), 8 batches. grid 512 x 512 thr.
// P[z] = exp(min(A[z] @ B[z]^T, 30)).
__global__ __launch_bounds__(512, 2) void gemm256p(
    const bf16* __restrict__ A, const bf16* __restrict__ Bm,
    bf16* __restrict__ P) {
    __shared__ __attribute__((aligned(16))) bf16 ls[2][2][16384];   // 128 KiB
    const int tid = threadIdx.x;
    const int lane = tid & 63, w = tid >> 6;
    const int wm = w >> 2, wn = w & 3;          // 2 x 4 waves
    const int id = blockIdx.x;
    const int sw = (id & 7) * 64 + (id >> 3);   // batch z == XCD
    const int z = sw >> 6, tt = sw & 63;
    const int bm = (tt >> 3) * 256, bn = (tt & 7) * 256;
    const bf16* Ab = A + (size_t)z * N_ * C_;
    const bf16* Bb = Bm + (size_t)z * N_ * C_;

    f32x4 acc[8][4];
#pragma unroll
    for (int i = 0; i < 8; ++i)
#pragma unroll
        for (int j = 0; j < 4; ++j) acc[i][j] = f32x4{0.f, 0.f, 0.f, 0.f};

    // Stage half-tile h (128 rows) of A or B for K-tile kt_ into buf_.
    // Linear LDS dest (wave-uniform base) + inverse-swizzled global source.
#define STAGE_H(MATP, BASE, h, kt_, buf_, abi)                                    \
    {                                                                             \
        _Pragma("unroll")                                                         \
        for (int sl = 0; sl < 2; ++sl) {                                          \
            int cc = sl * 512 + tid;                                              \
            int row = (h) * 128 + (cc >> 3);                                      \
            int qd = (cc & 7) ^ (row & 7);                                        \
            gload_lds16(MATP + (size_t)((BASE) + row) * C_ + (kt_) * 64 + qd * 8, \
                        &ls[buf_][abi][((h) * 1024 + sl * 512 + w * 64) * 8]);    \
        }                                                                         \
    }
#define PH_SYNC_MFMA                                                    \
    __builtin_amdgcn_s_barrier();                                       \
    asm volatile("s_waitcnt lgkmcnt(0)" ::: "memory");                  \
    __builtin_amdgcn_sched_barrier(0);                                  \
    __builtin_amdgcn_s_setprio(1);

    // prologue: T0 fully + B halves of T1 (mimics steady-state j=-1 p2/p3)
    STAGE_H(Ab, bm, 0, 0, 0, 0); STAGE_H(Ab, bm, 1, 0, 0, 0);
    STAGE_H(Bb, bn, 0, 0, 0, 1); STAGE_H(Bb, bn, 1, 0, 0, 1);
    STAGE_H(Bb, bn, 0, 1, 1, 1); STAGE_H(Bb, bn, 1, 1, 1, 1);
    asm volatile("s_waitcnt vmcnt(4)" ::: "memory");   // T0 landed; B(T1) in flight
    __builtin_amdgcn_s_barrier();

#pragma unroll
    for (int j = 0; j < 8; ++j) {
        const int cur = j & 1, nxt = cur ^ 1;
        const bf16* lA = &ls[cur][0][0];
        const bf16* lB = &ls[cur][1][0];
        bf16x8 af[4][2], b0[2][2], b1v[2][2];

        // ---- p0: read A(a=0) 8 + B(bq=0) 4; stage A-h0(j+1) ----
#pragma unroll
        for (int i = 0; i < 4; ++i) {
            int ra = wm * 128 + i * 16 + (lane & 15);
#pragma unroll
            for (int ks = 0; ks < 2; ++ks) {
                int y = ks * 4 + (lane >> 4);
                af[i][ks] = *(const bf16x8*)&lA[ra * 64 + ((y ^ (ra & 7)) * 8)];
            }
        }
#pragma unroll
        for (int jj = 0; jj < 2; ++jj) {
            int rb = wn * 64 + jj * 16 + (lane & 15);
#pragma unroll
            for (int ks = 0; ks < 2; ++ks) {
                int y = ks * 4 + (lane >> 4);
                b0[jj][ks] = *(const bf16x8*)&lB[rb * 64 + ((y ^ (rb & 7)) * 8)];
            }
        }
        if (j < 7) STAGE_H(Ab, bm, 0, j + 1, nxt, 0);
        PH_SYNC_MFMA
#pragma unroll
        for (int ks = 0; ks < 2; ++ks)
#pragma unroll
            for (int i = 0; i < 4; ++i)
#pragma unroll
                for (int jj = 0; jj < 2; ++jj)
                    acc[i][jj] = __builtin_amdgcn_mfma_f32_16x16x32_bf16(
                        af[i][ks], b0[jj][ks], acc[i][jj], 0, 0, 0);
        __builtin_amdgcn_s_setprio(0);
        __builtin_amdgcn_s_barrier();

        // ---- p1: read B(bq=1) 4; stage A-h1(j+1) ----
#pragma unroll
        for (int jj = 0; jj < 2; ++jj) {
            int rb = wn * 64 + 32 + jj * 16 + (lane & 15);
#pragma unroll
            for (int ks = 0; ks < 2; ++ks) {
                int y = ks * 4 + (lane >> 4);
                b1v[jj][ks] = *(const bf16x8*)&lB[rb * 64 + ((y ^ (rb & 7)) * 8)];
            }
        }
        if (j < 7) STAGE_H(Ab, bm, 1, j + 1, nxt, 0);
        PH_SYNC_MFMA
#pragma unroll
        for (int ks = 0; ks < 2; ++ks)
#pragma unroll
            for (int i = 0; i < 4; ++i)
#pragma unroll
                for (int jj = 0; jj < 2; ++jj)
                    acc[i][2 + jj] = __builtin_amdgcn_mfma_f32_16x16x32_bf16(
                        af[i][ks], b1v[jj][ks], acc[i][2 + jj], 0, 0, 0);
        __builtin_amdgcn_s_setprio(0);
        __builtin_amdgcn_s_barrier();

        // ---- p2: read A(a=1) 8 (reuse af regs); stage B-h0(j+2) ----
#pragma unroll
        for (int i = 0; i < 4; ++i) {
            int ra = wm * 128 + 64 + i * 16 + (lane & 15);
#pragma unroll
            for (int ks = 0; ks < 2; ++ks) {
                int y = ks * 4 + (lane >> 4);
                af[i][ks] = *(const bf16x8*)&lA[ra * 64 + ((y ^ (ra & 7)) * 8)];
            }
        }
        if (j < 6) STAGE_H(Bb, bn, 0, j + 2, cur, 1);
        PH_SYNC_MFMA
#pragma unroll
        for (int ks = 0; ks < 2; ++ks)
#pragma unroll
            for (int i = 0; i < 4; ++i)
#pragma unroll
                for (int jj = 0; jj < 2; ++jj)
                    acc[4 + i][jj] = __builtin_amdgcn_mfma_f32_16x16x32_bf16(
                        af[i][ks], b0[jj][ks], acc[4 + i][jj], 0, 0, 0);
        __builtin_amdgcn_s_setprio(0);
        __builtin_amdgcn_s_barrier();

        // ---- p3: no reads; stage B-h1(j+2); counted vmcnt guards next tile ----
        if (j < 6) {
            STAGE_H(Bb, bn, 1, j + 2, cur, 1);
            asm volatile("s_waitcnt vmcnt(4)" ::: "memory");  // tile j+1 landed
        } else if (j == 6) {
            asm volatile("s_waitcnt vmcnt(0)" ::: "memory");  // T7 landed
        }
        __builtin_amdgcn_s_barrier();
        __builtin_amdgcn_s_setprio(1);
#pragma unroll
        for (int ks = 0; ks < 2; ++ks)
#pragma unroll
            for (int i = 0; i < 4; ++i)
#pragma unroll
                for (int jj = 0; jj < 2; ++jj)
                    acc[4 + i][2 + jj] = __builtin_amdgcn_mfma_f32_16x16x32_bf16(
                        af[i][ks], b1v[jj][ks], acc[4 + i][2 + jj], 0, 0, 0);
        __builtin_amdgcn_s_setprio(0);
        __builtin_amdgcn_s_barrier();
    }

    // epilogue: direct stores with exp
    bf16* Pb = P + (size_t)z * N_ * N_;
#pragma unroll
    for (int fi = 0; fi < 8; ++fi) {
#pragma unroll
        for (int fj = 0; fj < 4; ++fj) {
            int roff = (fi >> 2) * 64 + (fi & 3) * 16;
            int coff = (fj >> 1) * 32 + (fj & 1) * 16;
            int col = bn + wn * 64 + coff + (lane & 15);
#pragma unroll
            for (int r = 0; r < 4; ++r) {
                int row = bm + wm * 128 + roff + (lane >> 4) * 4 + r;
                float v = __expf(fminf(acc[fi][fj][r], 30.f));
                Pb[(size_t)row * N_ + col] = (bf16)v;
            }
        }
    }
#undef STAGE_H
#undef PH_SYNC_MFMA
}

// Single-read softmax column-sums: block (s,b) owns 16 rows x all 2048 cols.
__global__ __launch_bounds__(256) void k_w2(const bf16* __restrict__ P,
                                            float* __restrict__ wpart) {
    __shared__ float rp[16 * 256];
    __shared__ float ri[16];
    const int tid = threadIdx.x;
    const int s = blockIdx.x, b = blockIdx.y;
    const bf16* Pb = P + (size_t)b * N_ * N_ + (size_t)s * 16 * N_;
    const int j0 = tid * 8;
    bf16x8 v[16];
#pragma unroll
    for (int r = 0; r < 16; ++r) {
        v[r] = *(const bf16x8*)&Pb[(size_t)r * N_ + j0];
        float t = 0.f;
#pragma unroll
        for (int e = 0; e < 8; ++e) t += (float)v[r][e];
        rp[r * 256 + tid] = t;
    }
    __syncthreads();
    {
        int row = tid >> 4, seg = tid & 15;
        float t = 0.f;
#pragma unroll
        for (int k = 0; k < 16; ++k) t += rp[row * 256 + seg + 16 * k];
#pragma unroll
        for (int m = 8; m; m >>= 1) t += __shfl_xor(t, m);
        if (seg == 0) ri[row] = 1.0f / t;
    }
    __syncthreads();
    float acc8[8] = {0.f, 0.f, 0.f, 0.f, 0.f, 0.f, 0.f, 0.f};
#pragma unroll
    for (int r = 0; r < 16; ++r) {
        float rr = ri[r];
#pragma unroll
        for (int e = 0; e < 8; ++e) acc8[e] += rr * (float)v[r][e];
    }
    float* wp = wpart + ((size_t)b * 128 + s) * (size_t)N_;
#pragma unroll
    for (int e = 0; e < 8; ++e) wp[j0 + e] = acc8[e];
}

// Block (slab,b): w[j] = 1 + sum_s wpart[b][s][j], then
// gppart[slab][b][c] = sum_j w[j]*nodes_bf[b][j][c]. No atomics.
__global__ __launch_bounds__(256) void k_gp(const bf16* __restrict__ nodes_bf,
                                            const float* __restrict__ wpart,
                                            float* __restrict__ gppart) {
    __shared__ float wred[4][64];
    __shared__ float wsh[64];
    __shared__ float gred[4][512];
    const int tid = threadIdx.x;
    const int slab = blockIdx.x, b = blockIdx.y;
    const int jj = tid & 63, sg = tid >> 6;
    float wacc = 0.f;
    for (int s = sg; s < 128; s += 4)
        wacc += wpart[((size_t)b * 128 + s) * N_ + slab * 64 + jj];
    wred[sg][jj] = wacc;
    __syncthreads();
    if (tid < 64)
        wsh[tid] = wred[0][tid] + wred[1][tid] + wred[2][tid] + wred[3][tid] + 1.0f;
    __syncthreads();
    const int j0 = slab * 64;
    const int cc = (tid & 63) * 8, jr = tid >> 6;
    const bf16* nb = nodes_bf + (size_t)b * N_ * C_;
    float acc8[8] = {0.f, 0.f, 0.f, 0.f, 0.f, 0.f, 0.f, 0.f};
    for (int j = jr; j < 64; j += 4) {
        float wj = wsh[j];
        bf16x8 nv = *(const bf16x8*)&nb[(size_t)(j0 + j) * C_ + cc];
#pragma unroll
        for (int e = 0; e < 8; ++e) acc8[e] += wj * (float)nv[e];
    }
#pragma unroll
    for (int e = 0; e < 8; ++e) gred[jr][cc + e] = acc8[e];
    __syncthreads();
    if (tid < 64) {
#pragma unroll
        for (int e = 0; e < 8; ++e) {
            int c = tid * 8 + e;
            gppart[((size_t)slab * 8 + b) * C_ + c] =
                gred[0][c] + gred[1][c] + gred[2][c] + gred[3][c];
        }
    }
}

// out[b][512+c] = (1/N) * sum_slab gppart[slab][b][c]
__global__ void k_fin(const float* __restrict__ gppart, float* __restrict__ out) {
    int gt = blockIdx.x * 256 + threadIdx.x;
    int b = gt >> 9, c = gt & 511;
    float s = 0.f;
#pragma unroll
    for (int k = 0; k < 32; ++k) s += gppart[((size_t)k * 8 + b) * C_ + c];
    out[b * 2 * C_ + C_ + c] = s * (1.0f / N_);
}

extern "C" void kernel_launch(void* const* d_in, const int* in_sizes, int n_in,
                              void* d_out, int out_size, void* d_ws, size_t ws_size,
                              hipStream_t stream) {
    const float* vd_s  = (const float*)d_in[0];
    const float* nodes = (const float*)d_in[1];
    const float* W1    = (const float*)d_in[2];
    const float* b1    = (const float*)d_in[3];
    const float* W2    = (const float*)d_in[4];
    // d_in[5] (b2) adds a row-constant to adj -> cancels in row-softmax -> unused
    float* out = (float*)d_out;

    char* ws = (char*)d_ws;
    bf16*  nodes_bf = (bf16*)(ws);                                   // 16 MB
    bf16*  H2       = (bf16*)(ws + ((size_t)16 << 20));              // 16 MB
    float* wpart    = (float*)(ws + ((size_t)16 << 20));             // 8 MB, overlays H2
    bf16*  P        = (bf16*)(ws + ((size_t)32 << 20));              // 64 MB
    bf16*  W1t      = (bf16*)(ws + ((size_t)96 << 20));              // 512 KB
    bf16*  W2t      = (bf16*)(ws + ((size_t)96 << 20) + (512u << 10));
    bf16*  Gt       = (bf16*)(ws + ((size_t)96 << 20) + (1024u << 10));
    char*  fbase    = ws + ((size_t)96 << 20) + (1536u << 10);
    float* q        = (float*)(fbase);                     // 2 KB
    float* gppart   = (float*)(fbase + 4096);              // 512 KB

    k_prep<<<2576, 256, 0, stream>>>(vd_s, nodes, W1, W2,
                                     out, nodes_bf, W1t, W2t);
    k_q<<<128, 256, 0, stream>>>(b1, W2t, q);

    // Gt[c][k] = sum_m W2t[c][m]*W1t[k][m]
    gemm_nt<<<dim3(4, 4, 1), 256, 0, stream>>>(
        W2t, 0, W1t, 0, nullptr, Gt, 0, C_, C_);
    // H2[b] = nodes_bf[b] @ Gt^T + q[col]
    gemm_nt<<<dim3(16, 4, 8), 256, 0, stream>>>(
        nodes_bf, (size_t)N_ * C_, Gt, 0, q,
        H2, (size_t)N_ * C_, C_, C_);
    // P[b] = exp(H2[b] @ nodes_bf[b]^T)   (256^2 m201-cadence)
    gemm256p<<<512, 512, 0, stream>>>(H2, nodes_bf, P);

    k_w2<<<dim3(128, 8), 256, 0, stream>>>(P, wpart);
    k_gp<<<dim3(32, 8), 256, 0, stream>>>(nodes_bf, wpart, gppart);
    k_fin<<<16, 256, 0, stream>>>(gppart, out);
}